// Round 1
// baseline (1703.519 us; speedup 1.0000x reference)
//
#include <hip/hip_runtime.h>

#define DMODEL 1024
#define DSTATE 16
#define DCONV  4
#define DINNER 2048
#define BSZ    2
#define LSEQ   2048
#define MTOT   (BSZ * LSEQ)   // 4096 rows for all GEMMs

__device__ __forceinline__ float silu_f(float v) { return v / (1.f + __expf(-v)); }

// C[M,N] = A[M,K] @ B[N,K]^T   (both row-major over K)
// MODE 0: plain store. MODE 1: softplus(C + bias[col]).
template<int MODE>
__global__ __launch_bounds__(256)
void sgemm_bt(const float* __restrict__ A, const float* __restrict__ B,
              const float* __restrict__ bias, float* __restrict__ C,
              int M, int N, int K) {
  // stride 68: bank = (4k + m) % 32 -> worst 2-way conflict (free), 16B-aligned rows
  __shared__ __align__(16) float As[16][68];
  __shared__ __align__(16) float Bs[16][68];
  const int tid = threadIdx.x;
  const int bm = blockIdx.y * 64;
  const int bn = blockIdx.x * 64;
  const int tx = tid & 15;         // col group
  const int ty = tid >> 4;         // row group
  const int lr = tid >> 2;         // load row 0..63
  const int lk = (tid & 3) << 2;   // load k offset 0,4,8,12
  const float* Ap = A + (size_t)(bm + lr) * K + lk;
  const float* Bp = B + (size_t)(bn + lr) * K + lk;
  float acc[4][4] = {{0.f, 0.f, 0.f, 0.f}, {0.f, 0.f, 0.f, 0.f},
                     {0.f, 0.f, 0.f, 0.f}, {0.f, 0.f, 0.f, 0.f}};
  for (int k0 = 0; k0 < K; k0 += 16) {
    float4 av = *(const float4*)(Ap + k0);
    float4 bv = *(const float4*)(Bp + k0);
    As[lk + 0][lr] = av.x; As[lk + 1][lr] = av.y;
    As[lk + 2][lr] = av.z; As[lk + 3][lr] = av.w;
    Bs[lk + 0][lr] = bv.x; Bs[lk + 1][lr] = bv.y;
    Bs[lk + 2][lr] = bv.z; Bs[lk + 3][lr] = bv.w;
    __syncthreads();
#pragma unroll
    for (int k = 0; k < 16; ++k) {
      float4 a4 = *(const float4*)&As[k][ty << 2];
      float4 b4 = *(const float4*)&Bs[k][tx << 2];
      float ar[4] = {a4.x, a4.y, a4.z, a4.w};
      float br[4] = {b4.x, b4.y, b4.z, b4.w};
#pragma unroll
      for (int i = 0; i < 4; ++i)
#pragma unroll
        for (int j = 0; j < 4; ++j)
          acc[i][j] = fmaf(ar[i], br[j], acc[i][j]);
    }
    __syncthreads();
  }
#pragma unroll
  for (int i = 0; i < 4; ++i) {
    const int row = bm + (ty << 2) + i;
#pragma unroll
    for (int j = 0; j < 4; ++j) {
      const int col = bn + (tx << 2) + j;
      float v = acc[i][j];
      if (MODE == 1) {
        v += bias[col];
        v = (v > 20.f) ? v : logf(1.f + __expf(v));   // softplus
      }
      C[(size_t)row * N + col] = v;
    }
  }
}

// depthwise causal conv1d (taps=4, left pad 3) + bias + SiLU
// xz layout [b][t][4096]; channel c comes from first half. Writes x_act [b][t][2048].
__global__ __launch_bounds__(256)
void conv_silu(const float* __restrict__ xz, const float* __restrict__ conv_w,
               const float* __restrict__ conv_b, float* __restrict__ xact) {
  const int i = blockIdx.x * 256 + threadIdx.x;  // over MTOT*DINNER = 2^23
  const int c = i & (DINNER - 1);
  const int t = (i >> 11) & (LSEQ - 1);
  const int b = i >> 22;
  float s = conv_b[c];
  const float* w = conv_w + c * DCONV;
#pragma unroll
  for (int k = 0; k < DCONV; ++k) {
    const int tt = t + k - (DCONV - 1);
    if (tt >= 0)
      s = fmaf(xz[((size_t)(b * LSEQ + tt) << 12) + c], w[k], s);
  }
  xact[i] = silu_f(s);
}

// Selective scan, one lane per (b, channel, state); 16 groups of 16 lanes per block.
// LDS-tiled over 16 timesteps for coalesced I/O; gating y*silu(z) fused into store.
__global__ __launch_bounds__(256)
void scan_gate(const float* __restrict__ dtb, const float* __restrict__ xact,
               const float* __restrict__ xz, const float* __restrict__ A_log,
               const float* __restrict__ Dp, float* __restrict__ yg) {
  __shared__ float dts[16][16];
  __shared__ float xts[16][16];
  __shared__ float yts[16][16];
  const int tid = threadIdx.x;
  const int gl = tid >> 4;               // group (channel) within block, 0..15
  const int s  = tid & 15;               // state
  const int g  = blockIdx.x * 16 + gl;   // global (b,c) chain id, 0..4095
  const int b  = g >> 11;                // / DINNER
  const int c  = g & (DINNER - 1);
  const int c0 = (blockIdx.x * 16) & (DINNER - 1);
  const float a  = -__expf(A_log[c * DSTATE + s]);
  const float dp = Dp[c];
  const int cl = tid & 15;               // coop-load channel
  const int tl = tid >> 4;               // coop-load timestep
  float h = 0.f;
  for (int t0 = 0; t0 < LSEQ; t0 += 16) {
    const size_t idx = ((size_t)(b * LSEQ + t0 + tl) << 11) + c0 + cl;
    dts[tl][cl] = dtb[idx];
    xts[tl][cl] = xact[idx];
    __syncthreads();
#pragma unroll
    for (int j = 0; j < 16; ++j) {
      const float dtv = dts[j][gl];
      const float xv  = xts[j][gl];
      h = fmaf(__expf(dtv * a), h, dtv * xv);   // h = exp(dt*A)*h + dt*x
      float sum = h;
      sum += __shfl_xor(sum, 1, 16);
      sum += __shfl_xor(sum, 2, 16);
      sum += __shfl_xor(sum, 4, 16);
      sum += __shfl_xor(sum, 8, 16);
      if (s == 0) yts[j][gl] = fmaf(dp, xv, sum);
    }
    __syncthreads();
    const float yv = yts[tl][cl];
    const float zv = xz[((size_t)(b * LSEQ + t0 + tl) << 12) + DINNER + c0 + cl];
    yg[idx] = yv * silu_f(zv);
    // no third barrier needed: next iter writes dts/xts (disjoint from yts reads),
    // and its yts writes are fenced behind the next __syncthreads()
  }
}

extern "C" void kernel_launch(void* const* d_in, const int* in_sizes, int n_in,
                              void* d_out, int out_size, void* d_ws, size_t ws_size,
                              hipStream_t stream) {
  const float* x      = (const float*)d_in[0];
  const float* W_in   = (const float*)d_in[1];
  const float* conv_w = (const float*)d_in[2];
  const float* conv_b = (const float*)d_in[3];
  const float* A_log  = (const float*)d_in[4];
  const float* Dp     = (const float*)d_in[5];
  const float* W_dt   = (const float*)d_in[6];
  const float* b_dt   = (const float*)d_in[7];
  const float* W_out  = (const float*)d_in[8];
  float* out = (float*)d_out;

  float* ws   = (float*)d_ws;
  float* xz   = ws;                                    // [4096, 4096]  64 MB
  float* xact = xz   + (size_t)MTOT * 2 * DINNER;      // [4096, 2048]  32 MB
  float* dtb  = xact + (size_t)MTOT * DINNER;          // [4096, 2048]  32 MB
  float* yg   = dtb  + (size_t)MTOT * DINNER;          // [4096, 2048]  32 MB

  const dim3 blk(256);

  // 1) xz = x @ W_in^T
  sgemm_bt<0><<<dim3(2 * DINNER / 64, MTOT / 64), blk, 0, stream>>>(
      x, W_in, nullptr, xz, MTOT, 2 * DINNER, DMODEL);
  // 2) x_act = silu(depthwise_causal_conv(x_proj) + conv_b)
  conv_silu<<<dim3((MTOT * DINNER) / 256), blk, 0, stream>>>(xz, conv_w, conv_b, xact);
  // 3) dt = softplus(x_act @ W_dt^T + b_dt)
  sgemm_bt<1><<<dim3(DINNER / 64, MTOT / 64), blk, 0, stream>>>(
      xact, W_dt, b_dt, dtb, MTOT, DINNER, DINNER);
  // 4) selective scan + D skip + gate by silu(z)
  scan_gate<<<dim3(BSZ * DINNER / 16), blk, 0, stream>>>(dtb, xact, xz, A_log, Dp, yg);
  // 5) out = y_gated @ W_out^T
  sgemm_bt<0><<<dim3(DMODEL / 64, MTOT / 64), blk, 0, stream>>>(
      yg, W_out, nullptr, out, MTOT, DMODEL, DINNER);
}

// Round 2
// 750.323 us; speedup vs baseline: 2.2704x; 2.2704x over previous
//
#include <hip/hip_runtime.h>

#define DMODEL 1024
#define DSTATE 16
#define DCONV  4
#define DINNER 2048
#define BSZ    2
#define LSEQ   2048
#define MTOT   (BSZ * LSEQ)   // 4096 rows for all GEMMs

typedef unsigned short u16;
typedef __attribute__((ext_vector_type(8))) short short8;  // 8 bf16 = 4 VGPRs (MFMA A/B frag)
typedef __attribute__((ext_vector_type(4))) float f32x4;   // MFMA C/D frag

__device__ __forceinline__ float silu_f(float v) { return v / (1.f + __expf(-v)); }

__device__ __forceinline__ u16 f2bf(float f) {   // RNE f32 -> bf16
  unsigned int u = __float_as_uint(f);
  u += 0x7FFF + ((u >> 16) & 1);
  return (u16)(u >> 16);
}
__device__ __forceinline__ float bf2f(u16 b) { return __uint_as_float(((unsigned int)b) << 16); }

// async global->LDS, 16B per lane; LDS dest is wave-uniform base + lane*16 (m104)
__device__ __forceinline__ void gload_lds16(const u16* g, u16* l) {
  __builtin_amdgcn_global_load_lds((const __attribute__((address_space(1))) unsigned int*)g,
                                   (__attribute__((address_space(3))) unsigned int*)l, 16, 0, 0);
}

__global__ __launch_bounds__(256)
void cast_bf16(const float4* __restrict__ s, ushort4* __restrict__ d, int n4) {
  int i = blockIdx.x * 256 + threadIdx.x;
  if (i >= n4) return;
  float4 v = s[i];
  ushort4 o = { f2bf(v.x), f2bf(v.y), f2bf(v.z), f2bf(v.w) };
  d[i] = o;
}

// C[M,N] = A[M,K] @ B[N,K]^T, bf16 inputs, fp32 out.
// m97 structure: 128x128 tile, BK=32, 4 waves, each wave 64x64 via 4x4 mfma_16x16x32 tiles.
// LDS K-major [row][32], 16B chunks XOR-swizzled by (row>>1)&3 -> 2-way max conflicts (free).
// MODE 0: plain store. MODE 1: softplus(C + bias[col]).
template<int MODE>
__global__ __launch_bounds__(256)
void hgemm_bt(const u16* __restrict__ A, const u16* __restrict__ B,
              const float* __restrict__ bias, float* __restrict__ C,
              int M, int N, int K) {
  __shared__ u16 As[128 * 32];   // 8 KB
  __shared__ u16 Bs[128 * 32];   // 8 KB
  const int tid  = threadIdx.x;
  const int lane = tid & 63;
  const int w    = tid >> 6;
  const int quad = lane >> 4;
  const int l16  = lane & 15;
  const int bm = blockIdx.y * 128;
  const int bn = blockIdx.x * 128;
  const int wm = (w & 1) * 64;
  const int wn = (w >> 1) * 64;

  // Staging geometry: wave w fills LDS segments s0,s1 (1 KB each = 16 rows).
  // chunk global idx cg -> row r = cg>>2, phys chunk p = cg&3, data chunk cd = p ^ ((r>>1)&3).
  const int s0 = w * 2, s1 = s0 + 1;
  const int cg0 = (s0 << 6) + lane, cg1 = (s1 << 6) + lane;
  const int r0 = cg0 >> 2, r1 = cg1 >> 2;
  const int cd0 = (cg0 & 3) ^ ((r0 >> 1) & 3);
  const int cd1 = (cg1 & 3) ^ ((r1 >> 1) & 3);
  const u16* Ag0 = A + (size_t)(bm + r0) * K + (cd0 << 3);
  const u16* Ag1 = A + (size_t)(bm + r1) * K + (cd1 << 3);
  const u16* Bg0 = B + (size_t)(bn + r0) * K + (cd0 << 3);
  const u16* Bg1 = B + (size_t)(bn + r1) * K + (cd1 << 3);
  u16* Al0 = &As[s0 << 9];
  u16* Al1 = &As[s1 << 9];
  u16* Bl0 = &Bs[s0 << 9];
  u16* Bl1 = &Bs[s1 << 9];

  // Fragment LDS pointers (K-invariant). A-frag: lane holds A[m=l16][k=quad*8+j].
  const short8* Afp[4];
  const short8* Bfp[4];
#pragma unroll
  for (int s = 0; s < 4; ++s) {
    const int ra = wm + 16 * s + l16;
    const int rb = wn + 16 * s + l16;
    Afp[s] = (const short8*)&As[ra * 32 + ((quad ^ ((ra >> 1) & 3)) << 3)];
    Bfp[s] = (const short8*)&Bs[rb * 32 + ((quad ^ ((rb >> 1) & 3)) << 3)];
  }

  f32x4 acc[4][4] = {};

  for (int k0 = 0; k0 < K; k0 += 32) {
    gload_lds16(Ag0, Al0); gload_lds16(Ag1, Al1);
    gload_lds16(Bg0, Bl0); gload_lds16(Bg1, Bl1);
    Ag0 += 32; Ag1 += 32; Bg0 += 32; Bg1 += 32;
    __syncthreads();   // drains vmcnt (DMA) before LDS reads
    short8 af[4], bf[4];
#pragma unroll
    for (int s = 0; s < 4; ++s) { af[s] = *Afp[s]; bf[s] = *Bfp[s]; }
#pragma unroll
    for (int ti = 0; ti < 4; ++ti)
#pragma unroll
      for (int tj = 0; tj < 4; ++tj)
        acc[ti][tj] = __builtin_amdgcn_mfma_f32_16x16x32_bf16(af[ti], bf[tj], acc[ti][tj], 0, 0, 0);
    __syncthreads();
  }

  // C/D layout: col = lane&15, row = quad*4 + reg (m89/m91 verified)
#pragma unroll
  for (int ti = 0; ti < 4; ++ti) {
    const int row0 = bm + wm + 16 * ti + quad * 4;
#pragma unroll
    for (int tj = 0; tj < 4; ++tj) {
      const int col = bn + wn + 16 * tj + l16;
      const float bv = (MODE == 1) ? bias[col] : 0.f;
#pragma unroll
      for (int i = 0; i < 4; ++i) {
        float v = acc[ti][tj][i] + bv;
        if (MODE == 1) v = (v > 20.f) ? v : __logf(1.f + __expf(v));   // softplus
        C[(size_t)(row0 + i) * N + col] = v;
      }
    }
  }
}

// depthwise causal conv1d (taps=4, left pad 3) + bias + SiLU; fp32 in, bf16 out
__global__ __launch_bounds__(256)
void conv_silu(const float* __restrict__ xz, const float* __restrict__ conv_w,
               const float* __restrict__ conv_b, u16* __restrict__ xact) {
  const int i = blockIdx.x * 256 + threadIdx.x;  // over MTOT*DINNER = 2^23
  const int c = i & (DINNER - 1);
  const int t = (i >> 11) & (LSEQ - 1);
  const int b = i >> 22;
  float s = conv_b[c];
  const float* w = conv_w + c * DCONV;
#pragma unroll
  for (int k = 0; k < DCONV; ++k) {
    const int tt = t + k - (DCONV - 1);
    if (tt >= 0)
      s = fmaf(xz[((size_t)(b * LSEQ + tt) << 12) + c], w[k], s);
  }
  xact[i] = f2bf(silu_f(s));
}

// Selective scan, one lane per (b, channel, state); fp32 math; gated bf16 output.
__global__ __launch_bounds__(256)
void scan_gate(const float* __restrict__ dtb, const u16* __restrict__ xact,
               const float* __restrict__ xz, const float* __restrict__ A_log,
               const float* __restrict__ Dp, u16* __restrict__ yg) {
  __shared__ float dts[16][16];
  __shared__ float xts[16][16];
  __shared__ float yts[16][16];
  const int tid = threadIdx.x;
  const int gl = tid >> 4;               // group (channel) within block
  const int s  = tid & 15;               // state
  const int g  = blockIdx.x * 16 + gl;   // global (b,c) chain id
  const int b  = g >> 11;
  const int c  = g & (DINNER - 1);
  const int c0 = (blockIdx.x * 16) & (DINNER - 1);
  const float a  = -__expf(A_log[c * DSTATE + s]);
  const float dp = Dp[c];
  const int cl = tid & 15;               // coop-load channel
  const int tl = tid >> 4;               // coop-load timestep
  float h = 0.f;
  for (int t0 = 0; t0 < LSEQ; t0 += 16) {
    const size_t idx = ((size_t)(b * LSEQ + t0 + tl) << 11) + c0 + cl;
    dts[tl][cl] = dtb[idx];
    xts[tl][cl] = bf2f(xact[idx]);
    __syncthreads();
#pragma unroll
    for (int j = 0; j < 16; ++j) {
      const float dtv = dts[j][gl];
      const float xv  = xts[j][gl];
      h = fmaf(__expf(dtv * a), h, dtv * xv);   // h = exp(dt*A)*h + dt*x
      float sum = h;
      sum += __shfl_xor(sum, 1, 16);
      sum += __shfl_xor(sum, 2, 16);
      sum += __shfl_xor(sum, 4, 16);
      sum += __shfl_xor(sum, 8, 16);
      if (s == 0) yts[j][gl] = fmaf(dp, xv, sum);
    }
    __syncthreads();
    const float yv = yts[tl][cl];
    const float zv = xz[((size_t)(b * LSEQ + t0 + tl) << 12) + DINNER + c0 + cl];
    yg[idx] = f2bf(yv * silu_f(zv));
  }
}

extern "C" void kernel_launch(void* const* d_in, const int* in_sizes, int n_in,
                              void* d_out, int out_size, void* d_ws, size_t ws_size,
                              hipStream_t stream) {
  const float* x      = (const float*)d_in[0];
  const float* W_in   = (const float*)d_in[1];
  const float* conv_w = (const float*)d_in[2];
  const float* conv_b = (const float*)d_in[3];
  const float* A_log  = (const float*)d_in[4];
  const float* Dp     = (const float*)d_in[5];
  const float* W_dt   = (const float*)d_in[6];
  const float* b_dt   = (const float*)d_in[7];
  const float* W_out  = (const float*)d_in[8];
  float* out = (float*)d_out;

  // workspace layout (total ~156 MB)
  float* ws  = (float*)d_ws;
  float* xz  = ws;                                    // [4096,4096] f32  64 MB
  float* dtb = xz + (size_t)MTOT * 2 * DINNER;        // [4096,2048] f32  32 MB
  u16* xbf   = (u16*)(dtb + (size_t)MTOT * DINNER);   // x bf16            8 MB
  u16* wibf  = xbf  + (size_t)MTOT * DMODEL;          // W_in bf16         8 MB
  u16* wdbf  = wibf + (size_t)2 * DINNER * DMODEL;    // W_dt bf16         8 MB
  u16* wobf  = wdbf + (size_t)DINNER * DINNER;        // W_out bf16        4 MB
  u16* xact  = wobf + (size_t)DMODEL * DINNER;        // x_act bf16       16 MB
  u16* yg    = xact + (size_t)MTOT * DINNER;          // y_gated bf16     16 MB

  const dim3 blk(256);

  // 0) casts to bf16 (inputs are re-poisoned every call, so cast every call)
  cast_bf16<<<MTOT * DMODEL / 4 / 256, blk, 0, stream>>>((const float4*)x, (ushort4*)xbf, MTOT * DMODEL / 4);
  cast_bf16<<<2 * DINNER * DMODEL / 4 / 256, blk, 0, stream>>>((const float4*)W_in, (ushort4*)wibf, 2 * DINNER * DMODEL / 4);
  cast_bf16<<<DINNER * DINNER / 4 / 256, blk, 0, stream>>>((const float4*)W_dt, (ushort4*)wdbf, DINNER * DINNER / 4);
  cast_bf16<<<DMODEL * DINNER / 4 / 256, blk, 0, stream>>>((const float4*)W_out, (ushort4*)wobf, DMODEL * DINNER / 4);

  // 1) xz = x @ W_in^T            [4096,4096] <- [4096,1024]x[4096,1024]^T
  hgemm_bt<0><<<dim3(2 * DINNER / 128, MTOT / 128), blk, 0, stream>>>(
      xbf, wibf, nullptr, xz, MTOT, 2 * DINNER, DMODEL);
  // 2) x_act = silu(conv(x_proj) + conv_b), bf16
  conv_silu<<<(MTOT * DINNER) / 256, blk, 0, stream>>>(xz, conv_w, conv_b, xact);
  // 3) dt = softplus(x_act @ W_dt^T + b_dt), fp32
  hgemm_bt<1><<<dim3(DINNER / 128, MTOT / 128), blk, 0, stream>>>(
      xact, wdbf, b_dt, dtb, MTOT, DINNER, DINNER);
  // 4) selective scan + D skip + gate, bf16 out
  scan_gate<<<BSZ * DINNER / 16, blk, 0, stream>>>(dtb, xact, xz, A_log, Dp, yg);
  // 5) out = y_gated @ W_out^T, fp32
  hgemm_bt<0><<<dim3(DMODEL / 128, MTOT / 128), blk, 0, stream>>>(
      yg, wobf, nullptr, out, MTOT, DMODEL, DINNER);
}

// Round 3
// 416.313 us; speedup vs baseline: 4.0919x; 1.8023x over previous
//
#include <hip/hip_runtime.h>

#define DMODEL 1024
#define DSTATE 16
#define DCONV  4
#define DINNER 2048
#define BSZ    2
#define LSEQ   2048
#define MTOT   (BSZ * LSEQ)   // 4096 rows for all GEMMs
#define NCH    64             // scan chunks per sequence
#define LC     (LSEQ / NCH)   // 32 timesteps per chunk
#define LOG2E  1.44269504088896f

typedef unsigned short u16;
typedef __attribute__((ext_vector_type(8))) short short8;  // 8 bf16 = 4 VGPRs (MFMA A/B frag)
typedef __attribute__((ext_vector_type(4))) float f32x4;   // MFMA C/D frag

__device__ __forceinline__ float silu_f(float v) { return v / (1.f + __expf(-v)); }

__device__ __forceinline__ u16 f2bf(float f) {   // RNE f32 -> bf16
  unsigned int u = __float_as_uint(f);
  u += 0x7FFF + ((u >> 16) & 1);
  return (u16)(u >> 16);
}
__device__ __forceinline__ float bf2f(u16 b) { return __uint_as_float(((unsigned int)b) << 16); }

// async global->LDS, 16B per lane; LDS dest is wave-uniform base + lane*16 (m104)
__device__ __forceinline__ void gload_lds16(const u16* g, u16* l) {
  __builtin_amdgcn_global_load_lds((const __attribute__((address_space(1))) unsigned int*)g,
                                   (__attribute__((address_space(3))) unsigned int*)l, 16, 0, 0);
}

__global__ __launch_bounds__(256)
void cast_bf16(const float4* __restrict__ s, ushort4* __restrict__ d, int n4) {
  int i = blockIdx.x * 256 + threadIdx.x;
  if (i >= n4) return;
  float4 v = s[i];
  ushort4 o = { f2bf(v.x), f2bf(v.y), f2bf(v.z), f2bf(v.w) };
  d[i] = o;
}

// C[M,N] = A[M,K] @ B[N,K]^T, bf16 inputs, fp32 out.
// m97 structure: 128x128 tile, BK=32, 4 waves, each wave 64x64 via 4x4 mfma_16x16x32 tiles.
// MODE 0: plain store. MODE 1: softplus(C + bias[col]).
template<int MODE>
__global__ __launch_bounds__(256)
void hgemm_bt(const u16* __restrict__ A, const u16* __restrict__ B,
              const float* __restrict__ bias, float* __restrict__ C,
              int M, int N, int K) {
  __shared__ u16 As[128 * 32];   // 8 KB
  __shared__ u16 Bs[128 * 32];   // 8 KB
  const int tid  = threadIdx.x;
  const int lane = tid & 63;
  const int w    = tid >> 6;
  const int quad = lane >> 4;
  const int l16  = lane & 15;
  const int bm = blockIdx.y * 128;
  const int bn = blockIdx.x * 128;
  const int wm = (w & 1) * 64;
  const int wn = (w >> 1) * 64;

  const int s0 = w * 2, s1 = s0 + 1;
  const int cg0 = (s0 << 6) + lane, cg1 = (s1 << 6) + lane;
  const int r0 = cg0 >> 2, r1 = cg1 >> 2;
  const int cd0 = (cg0 & 3) ^ ((r0 >> 1) & 3);
  const int cd1 = (cg1 & 3) ^ ((r1 >> 1) & 3);
  const u16* Ag0 = A + (size_t)(bm + r0) * K + (cd0 << 3);
  const u16* Ag1 = A + (size_t)(bm + r1) * K + (cd1 << 3);
  const u16* Bg0 = B + (size_t)(bn + r0) * K + (cd0 << 3);
  const u16* Bg1 = B + (size_t)(bn + r1) * K + (cd1 << 3);
  u16* Al0 = &As[s0 << 9];
  u16* Al1 = &As[s1 << 9];
  u16* Bl0 = &Bs[s0 << 9];
  u16* Bl1 = &Bs[s1 << 9];

  const short8* Afp[4];
  const short8* Bfp[4];
#pragma unroll
  for (int s = 0; s < 4; ++s) {
    const int ra = wm + 16 * s + l16;
    const int rb = wn + 16 * s + l16;
    Afp[s] = (const short8*)&As[ra * 32 + ((quad ^ ((ra >> 1) & 3)) << 3)];
    Bfp[s] = (const short8*)&Bs[rb * 32 + ((quad ^ ((rb >> 1) & 3)) << 3)];
  }

  f32x4 acc[4][4] = {};

  for (int k0 = 0; k0 < K; k0 += 32) {
    gload_lds16(Ag0, Al0); gload_lds16(Ag1, Al1);
    gload_lds16(Bg0, Bl0); gload_lds16(Bg1, Bl1);
    Ag0 += 32; Ag1 += 32; Bg0 += 32; Bg1 += 32;
    __syncthreads();
    short8 af[4], bf[4];
#pragma unroll
    for (int s = 0; s < 4; ++s) { af[s] = *Afp[s]; bf[s] = *Bfp[s]; }
#pragma unroll
    for (int ti = 0; ti < 4; ++ti)
#pragma unroll
      for (int tj = 0; tj < 4; ++tj)
        acc[ti][tj] = __builtin_amdgcn_mfma_f32_16x16x32_bf16(af[ti], bf[tj], acc[ti][tj], 0, 0, 0);
    __syncthreads();
  }

#pragma unroll
  for (int ti = 0; ti < 4; ++ti) {
    const int row0 = bm + wm + 16 * ti + quad * 4;
#pragma unroll
    for (int tj = 0; tj < 4; ++tj) {
      const int col = bn + wn + 16 * tj + l16;
      const float bv = (MODE == 1) ? bias[col] : 0.f;
#pragma unroll
      for (int i = 0; i < 4; ++i) {
        float v = acc[ti][tj][i] + bv;
        if (MODE == 1) v = (v > 20.f) ? v : __logf(1.f + __expf(v));   // softplus
        C[(size_t)(row0 + i) * N + col] = v;
      }
    }
  }
}

// depthwise causal conv1d (taps=4, left pad 3) + bias + SiLU; fp32 in, bf16 out
__global__ __launch_bounds__(256)
void conv_silu(const float* __restrict__ xz, const float* __restrict__ conv_w,
               const float* __restrict__ conv_b, u16* __restrict__ xact) {
  const int i = blockIdx.x * 256 + threadIdx.x;  // over MTOT*DINNER = 2^23
  const int c = i & (DINNER - 1);
  const int t = (i >> 11) & (LSEQ - 1);
  const int b = i >> 22;
  float s = conv_b[c];
  const float* w = conv_w + c * DCONV;
#pragma unroll
  for (int k = 0; k < DCONV; ++k) {
    const int tt = t + k - (DCONV - 1);
    if (tt >= 0)
      s = fmaf(xz[((size_t)(b * LSEQ + tt) << 12) + c], w[k], s);
  }
  xact[i] = f2bf(silu_f(s));
}

// ---- chunked parallel scan ------------------------------------------------
// h_t = exp(dt_t*a_s)*h_{t-1} + dt_t*x_t  is a linear recurrence; split L into
// NCH chunks. Lane owns (b, c, chunk) with all 16 states in registers.

// Pass 1: per-chunk local scan from h=0 -> h_end[16]; also sum(dt) over chunk
// (chunk decay prod_t exp(dt*a_s) == exp(a_s * sum dt), a_s const per lane).
__global__ __launch_bounds__(256)
void scan_pass1(const float* __restrict__ dtb, const u16* __restrict__ xact,
                const float* __restrict__ A_log,
                float* __restrict__ hbuf, float* __restrict__ sumdt) {
  const int gid = blockIdx.x * 256 + threadIdx.x;  // 2^18 lanes
  const int c  = gid & (DINNER - 1);
  const int ch = (gid >> 11) & (NCH - 1);
  const int b  = gid >> 17;
  float a2[16];
#pragma unroll
  for (int s = 0; s < 16; ++s)
    a2[s] = -__expf(A_log[c * DSTATE + s]) * LOG2E;   // exp(dt*a) = exp2(dt*a2)
  const size_t base = ((size_t)(b * LSEQ + ch * LC) << 11) + c;
  float h[16] = {};
  float sd = 0.f;
  for (int j = 0; j < LC; ++j) {
    const float dt = dtb[base + ((size_t)j << 11)];
    const float xv = bf2f(xact[base + ((size_t)j << 11)]);
    const float dx = dt * xv;
    sd += dt;
#pragma unroll
    for (int s = 0; s < 16; ++s)
      h[s] = fmaf(exp2f(dt * a2[s]), h[s], dx);
  }
  float4* ho = (float4*)&hbuf[(((size_t)(b * NCH + ch) * DINNER) + c) << 4];
#pragma unroll
  for (int q = 0; q < 4; ++q) {
    float4 v = { h[4 * q], h[4 * q + 1], h[4 * q + 2], h[4 * q + 3] };
    ho[q] = v;
  }
  sumdt[(size_t)(b * NCH + ch) * DINNER + c] = sd;
}

// Pass 2: serial combine over chunks; lane per (b,c,s). In-place: hbuf becomes
// h_start per chunk.
__global__ __launch_bounds__(256)
void scan_combine(float* __restrict__ hbuf, const float* __restrict__ sumdt,
                  const float* __restrict__ A_log) {
  const int gid = blockIdx.x * 256 + threadIdx.x;  // 2^16 lanes: b*32768 + c*16 + s
  const int s = gid & 15;
  const int c = (gid >> 4) & (DINNER - 1);
  const int b = gid >> 15;
  const float a2 = -__expf(A_log[c * DSTATE + s]) * LOG2E;
  float h = 0.f;
  for (int k = 0; k < NCH; ++k) {
    const size_t o = (((size_t)(b * NCH + k) * DINNER) + c) * 16 + s;
    const float he = hbuf[o];
    const float sd = sumdt[(size_t)(b * NCH + k) * DINNER + c];
    hbuf[o] = h;                          // h_start for chunk k
    h = fmaf(exp2f(sd * a2), h, he);
  }
}

// Pass 3: re-scan each chunk from its h_start; y = sum_s h + Dp*x; gate with
// silu(z); bf16 output.
__global__ __launch_bounds__(256)
void scan_pass3(const float* __restrict__ dtb, const u16* __restrict__ xact,
                const float* __restrict__ xz, const float* __restrict__ A_log,
                const float* __restrict__ Dp, const float* __restrict__ hbuf,
                u16* __restrict__ yg) {
  const int gid = blockIdx.x * 256 + threadIdx.x;
  const int c  = gid & (DINNER - 1);
  const int ch = (gid >> 11) & (NCH - 1);
  const int b  = gid >> 17;
  float a2[16];
#pragma unroll
  for (int s = 0; s < 16; ++s)
    a2[s] = -__expf(A_log[c * DSTATE + s]) * LOG2E;
  const float dp = Dp[c];
  float h[16];
  const float4* hi = (const float4*)&hbuf[(((size_t)(b * NCH + ch) * DINNER) + c) << 4];
#pragma unroll
  for (int q = 0; q < 4; ++q) {
    float4 v = hi[q];
    h[4 * q] = v.x; h[4 * q + 1] = v.y; h[4 * q + 2] = v.z; h[4 * q + 3] = v.w;
  }
  const size_t base = ((size_t)(b * LSEQ + ch * LC) << 11) + c;
  const size_t zbase = ((size_t)(b * LSEQ + ch * LC) << 12) + DINNER + c;
  for (int j = 0; j < LC; ++j) {
    const float dt = dtb[base + ((size_t)j << 11)];
    const float xv = bf2f(xact[base + ((size_t)j << 11)]);
    const float dx = dt * xv;
#pragma unroll
    for (int s = 0; s < 16; ++s)
      h[s] = fmaf(exp2f(dt * a2[s]), h[s], dx);
    float y = 0.f;
#pragma unroll
    for (int q = 0; q < 4; ++q) {
      float p = (h[4 * q] + h[4 * q + 1]) + (h[4 * q + 2] + h[4 * q + 3]);
      y += p;
    }
    y = fmaf(dp, xv, y);
    const float zv = xz[zbase + ((size_t)j << 12)];
    yg[base + ((size_t)j << 11)] = f2bf(y * silu_f(zv));
  }
}

extern "C" void kernel_launch(void* const* d_in, const int* in_sizes, int n_in,
                              void* d_out, int out_size, void* d_ws, size_t ws_size,
                              hipStream_t stream) {
  const float* x      = (const float*)d_in[0];
  const float* W_in   = (const float*)d_in[1];
  const float* conv_w = (const float*)d_in[2];
  const float* conv_b = (const float*)d_in[3];
  const float* A_log  = (const float*)d_in[4];
  const float* Dp     = (const float*)d_in[5];
  const float* W_dt   = (const float*)d_in[6];
  const float* b_dt   = (const float*)d_in[7];
  const float* W_out  = (const float*)d_in[8];
  float* out = (float*)d_out;

  // workspace layout
  float* ws    = (float*)d_ws;
  float* xz    = ws;                                    // [4096,4096] f32  64 MB
  float* dtb   = xz + (size_t)MTOT * 2 * DINNER;        // [4096,2048] f32  32 MB
  float* hbuf  = dtb + (size_t)MTOT * DINNER;           // [B,NCH,D,16] f32 16 MB
  float* sumdt = hbuf + (size_t)BSZ * NCH * DINNER * 16;// [B,NCH,D]   f32   1 MB
  u16* xbf   = (u16*)(sumdt + (size_t)BSZ * NCH * DINNER);
  u16* wibf  = xbf  + (size_t)MTOT * DMODEL;            // W_in bf16         8 MB
  u16* wdbf  = wibf + (size_t)2 * DINNER * DMODEL;      // W_dt bf16         8 MB
  u16* wobf  = wdbf + (size_t)DINNER * DINNER;          // W_out bf16        4 MB
  u16* xact  = wobf + (size_t)DMODEL * DINNER;          // x_act bf16       16 MB
  u16* yg    = xact + (size_t)MTOT * DINNER;            // y_gated bf16     16 MB

  const dim3 blk(256);

  // 0) casts to bf16
  cast_bf16<<<MTOT * DMODEL / 4 / 256, blk, 0, stream>>>((const float4*)x, (ushort4*)xbf, MTOT * DMODEL / 4);
  cast_bf16<<<2 * DINNER * DMODEL / 4 / 256, blk, 0, stream>>>((const float4*)W_in, (ushort4*)wibf, 2 * DINNER * DMODEL / 4);
  cast_bf16<<<DINNER * DINNER / 4 / 256, blk, 0, stream>>>((const float4*)W_dt, (ushort4*)wdbf, DINNER * DINNER / 4);
  cast_bf16<<<DMODEL * DINNER / 4 / 256, blk, 0, stream>>>((const float4*)W_out, (ushort4*)wobf, DMODEL * DINNER / 4);

  // 1) xz = x @ W_in^T
  hgemm_bt<0><<<dim3(2 * DINNER / 128, MTOT / 128), blk, 0, stream>>>(
      xbf, wibf, nullptr, xz, MTOT, 2 * DINNER, DMODEL);
  // 2) x_act = silu(conv(x_proj) + conv_b), bf16
  conv_silu<<<(MTOT * DINNER) / 256, blk, 0, stream>>>(xz, conv_w, conv_b, xact);
  // 3) dt = softplus(x_act @ W_dt^T + b_dt), fp32
  hgemm_bt<1><<<dim3(DINNER / 128, MTOT / 128), blk, 0, stream>>>(
      xact, wdbf, b_dt, dtb, MTOT, DINNER, DINNER);
  // 4) chunked selective scan + D skip + gate
  scan_pass1<<<BSZ * NCH * DINNER / 256, blk, 0, stream>>>(dtb, xact, A_log, hbuf, sumdt);
  scan_combine<<<BSZ * DINNER * 16 / 256, blk, 0, stream>>>(hbuf, sumdt, A_log);
  scan_pass3<<<BSZ * NCH * DINNER / 256, blk, 0, stream>>>(dtb, xact, xz, A_log, Dp, hbuf, yg);
  // 5) out = y_gated @ W_out^T
  hgemm_bt<0><<<dim3(DMODEL / 128, MTOT / 128), blk, 0, stream>>>(
      yg, wobf, nullptr, out, MTOT, DMODEL, DINNER);
}

// Round 4
// 400.803 us; speedup vs baseline: 4.2503x; 1.0387x over previous
//
#include <hip/hip_runtime.h>

#define DMODEL 1024
#define DSTATE 16
#define DCONV  4
#define DINNER 2048
#define BSZ    2
#define LSEQ   2048
#define MTOT   (BSZ * LSEQ)   // 4096 rows for all GEMMs
#define NCH    64             // scan chunks per sequence
#define LC     (LSEQ / NCH)   // 32 timesteps per chunk
#define LOG2E  1.44269504088896f

typedef unsigned short u16;
typedef __attribute__((ext_vector_type(8))) short short8;  // 8 bf16 = 4 VGPRs (MFMA A/B frag)
typedef __attribute__((ext_vector_type(4))) float f32x4;   // MFMA C/D frag

__device__ __forceinline__ float silu_f(float v) { return v / (1.f + __expf(-v)); }

__device__ __forceinline__ u16 f2bf(float f) {   // RNE f32 -> bf16
  unsigned int u = __float_as_uint(f);
  u += 0x7FFF + ((u >> 16) & 1);
  return (u16)(u >> 16);
}
__device__ __forceinline__ float bf2f(u16 b) { return __uint_as_float(((unsigned int)b) << 16); }

// async global->LDS, 16B per lane; LDS dest is wave-uniform base + lane*16 (m104)
__device__ __forceinline__ void gload_lds16(const u16* g, u16* l) {
  __builtin_amdgcn_global_load_lds((const __attribute__((address_space(1))) unsigned int*)g,
                                   (__attribute__((address_space(3))) unsigned int*)l, 16, 0, 0);
}

// All four f32->bf16 casts in one dispatch (x, W_in, W_dt, W_out)
__global__ __launch_bounds__(256)
void cast4(const float4* __restrict__ s0, ushort4* __restrict__ d0, int n0,
           const float4* __restrict__ s1, ushort4* __restrict__ d1, int n1,
           const float4* __restrict__ s2, ushort4* __restrict__ d2, int n2,
           const float4* __restrict__ s3, ushort4* __restrict__ d3, int n3) {
  int i = blockIdx.x * 256 + threadIdx.x;
  const float4* s; ushort4* d;
  if (i < n0)                { s = s0; d = d0; }
  else if ((i -= n0) < n1)   { s = s1; d = d1; }
  else if ((i -= n1) < n2)   { s = s2; d = d2; }
  else if ((i -= n2) < n3)   { s = s3; d = d3; }
  else return;
  float4 v = s[i];
  ushort4 o = { f2bf(v.x), f2bf(v.y), f2bf(v.z), f2bf(v.w) };
  d[i] = o;
}

// C[M,N] = A[M,K] @ B[N,K]^T, bf16 inputs.
// m97 structure: 128x128 tile, BK=32, 4 waves, 4x4 mfma_16x16x32 tiles per wave.
// 1-D grid with GROUP_M=4 panel swizzle for L2 locality.
// MODE 0: plain. MODE 1: softplus(C + bias[col]).  OBF: 1 -> bf16 C, 0 -> fp32 C.
template<int MODE, int OBF>
__global__ __launch_bounds__(256)
void hgemm_bt(const u16* __restrict__ A, const u16* __restrict__ B,
              const float* __restrict__ bias, void* __restrict__ Cv,
              int M, int N, int K) {
  __shared__ u16 As[128 * 32];   // 8 KB
  __shared__ u16 Bs[128 * 32];   // 8 KB
  const int tid  = threadIdx.x;
  const int lane = tid & 63;
  const int w    = tid >> 6;
  const int quad = lane >> 4;
  const int l16  = lane & 15;

  // GROUP_M=4 panel swizzle (triton-style): blocks in a panel share A rows
  const int nbn = N >> 7, nbm = M >> 7;
  const int pid = blockIdx.x;
  const int npg = 4 * nbn;
  const int fm  = (pid / npg) * 4;
  const int gsz = (nbm - fm < 4) ? (nbm - fm) : 4;
  const int bm  = (fm + (pid % gsz)) << 7;
  const int bn  = ((pid % npg) / gsz) << 7;

  const int wm = (w & 1) * 64;
  const int wn = (w >> 1) * 64;

  const int s0 = w * 2, s1 = s0 + 1;
  const int cg0 = (s0 << 6) + lane, cg1 = (s1 << 6) + lane;
  const int r0 = cg0 >> 2, r1 = cg1 >> 2;
  const int cd0 = (cg0 & 3) ^ ((r0 >> 1) & 3);
  const int cd1 = (cg1 & 3) ^ ((r1 >> 1) & 3);
  const u16* Ag0 = A + (size_t)(bm + r0) * K + (cd0 << 3);
  const u16* Ag1 = A + (size_t)(bm + r1) * K + (cd1 << 3);
  const u16* Bg0 = B + (size_t)(bn + r0) * K + (cd0 << 3);
  const u16* Bg1 = B + (size_t)(bn + r1) * K + (cd1 << 3);
  u16* Al0 = &As[s0 << 9];
  u16* Al1 = &As[s1 << 9];
  u16* Bl0 = &Bs[s0 << 9];
  u16* Bl1 = &Bs[s1 << 9];

  const short8* Afp[4];
  const short8* Bfp[4];
#pragma unroll
  for (int s = 0; s < 4; ++s) {
    const int ra = wm + 16 * s + l16;
    const int rb = wn + 16 * s + l16;
    Afp[s] = (const short8*)&As[ra * 32 + ((quad ^ ((ra >> 1) & 3)) << 3)];
    Bfp[s] = (const short8*)&Bs[rb * 32 + ((quad ^ ((rb >> 1) & 3)) << 3)];
  }

  f32x4 acc[4][4] = {};

  for (int k0 = 0; k0 < K; k0 += 32) {
    gload_lds16(Ag0, Al0); gload_lds16(Ag1, Al1);
    gload_lds16(Bg0, Bl0); gload_lds16(Bg1, Bl1);
    Ag0 += 32; Ag1 += 32; Bg0 += 32; Bg1 += 32;
    __syncthreads();
    short8 af[4], bf[4];
#pragma unroll
    for (int s = 0; s < 4; ++s) { af[s] = *Afp[s]; bf[s] = *Bfp[s]; }
#pragma unroll
    for (int ti = 0; ti < 4; ++ti)
#pragma unroll
      for (int tj = 0; tj < 4; ++tj)
        acc[ti][tj] = __builtin_amdgcn_mfma_f32_16x16x32_bf16(af[ti], bf[tj], acc[ti][tj], 0, 0, 0);
    __syncthreads();
  }

  // C/D layout: col = lane&15, row = quad*4 + reg (m89/m91)
#pragma unroll
  for (int ti = 0; ti < 4; ++ti) {
    const int row0 = bm + wm + 16 * ti + quad * 4;
#pragma unroll
    for (int tj = 0; tj < 4; ++tj) {
      const int col = bn + wn + 16 * tj + l16;
      const float bv = (MODE == 1) ? bias[col] : 0.f;
#pragma unroll
      for (int i = 0; i < 4; ++i) {
        float v = acc[ti][tj][i] + bv;
        if (MODE == 1) v = (v > 20.f) ? v : __logf(1.f + __expf(v));   // softplus
        if (OBF) ((u16*)Cv)[(size_t)(row0 + i) * N + col] = f2bf(v);
        else     ((float*)Cv)[(size_t)(row0 + i) * N + col] = v;
      }
    }
  }
}

// depthwise causal conv1d (taps=4, left pad 3) + bias + SiLU; bf16 in/out
__global__ __launch_bounds__(256)
void conv_silu(const u16* __restrict__ xz, const float* __restrict__ conv_w,
               const float* __restrict__ conv_b, u16* __restrict__ xact) {
  const int i = blockIdx.x * 256 + threadIdx.x;  // over MTOT*DINNER = 2^23
  const int c = i & (DINNER - 1);
  const int t = (i >> 11) & (LSEQ - 1);
  const int b = i >> 22;
  float s = conv_b[c];
  const float* w = conv_w + c * DCONV;
#pragma unroll
  for (int k = 0; k < DCONV; ++k) {
    const int tt = t + k - (DCONV - 1);
    if (tt >= 0)
      s = fmaf(bf2f(xz[((size_t)(b * LSEQ + tt) << 12) + c]), w[k], s);
  }
  xact[i] = f2bf(silu_f(s));
}

// ---- chunked parallel scan (exact decomposition of the linear recurrence) --

// Pass 1: per-chunk local scan from h=0 -> h_end[16]; also sum(dt) over chunk.
__global__ __launch_bounds__(256)
void scan_pass1(const u16* __restrict__ dtb, const u16* __restrict__ xact,
                const float* __restrict__ A_log,
                float* __restrict__ hbuf, float* __restrict__ sumdt) {
  const int gid = blockIdx.x * 256 + threadIdx.x;  // 2^18 lanes
  const int c  = gid & (DINNER - 1);
  const int ch = (gid >> 11) & (NCH - 1);
  const int b  = gid >> 17;
  float a2[16];
#pragma unroll
  for (int s = 0; s < 16; ++s)
    a2[s] = -__expf(A_log[c * DSTATE + s]) * LOG2E;   // exp(dt*a) = exp2(dt*a2)
  const size_t base = ((size_t)(b * LSEQ + ch * LC) << 11) + c;
  float h[16] = {};
  float sd = 0.f;
  for (int j = 0; j < LC; ++j) {
    const float dt = bf2f(dtb[base + ((size_t)j << 11)]);
    const float xv = bf2f(xact[base + ((size_t)j << 11)]);
    const float dx = dt * xv;
    sd += dt;
#pragma unroll
    for (int s = 0; s < 16; ++s)
      h[s] = fmaf(exp2f(dt * a2[s]), h[s], dx);
  }
  float4* ho = (float4*)&hbuf[(((size_t)(b * NCH + ch) * DINNER) + c) << 4];
#pragma unroll
  for (int q = 0; q < 4; ++q) {
    float4 v = { h[4 * q], h[4 * q + 1], h[4 * q + 2], h[4 * q + 3] };
    ho[q] = v;
  }
  sumdt[(size_t)(b * NCH + ch) * DINNER + c] = sd;
}

// Pass 2: serial combine over chunks; lane per (b,c,s). hbuf becomes h_start.
__global__ __launch_bounds__(256)
void scan_combine(float* __restrict__ hbuf, const float* __restrict__ sumdt,
                  const float* __restrict__ A_log) {
  const int gid = blockIdx.x * 256 + threadIdx.x;  // 2^16: b*32768 + c*16 + s
  const int s = gid & 15;
  const int c = (gid >> 4) & (DINNER - 1);
  const int b = gid >> 15;
  const float a2 = -__expf(A_log[c * DSTATE + s]) * LOG2E;
  float h = 0.f;
  for (int k = 0; k < NCH; ++k) {
    const size_t o = (((size_t)(b * NCH + k) * DINNER) + c) * 16 + s;
    const float he = hbuf[o];
    const float sd = sumdt[(size_t)(b * NCH + k) * DINNER + c];
    hbuf[o] = h;                          // h_start for chunk k
    h = fmaf(exp2f(sd * a2), h, he);
  }
}

// Pass 3: re-scan each chunk from h_start; y = sum_s h + Dp*x; gate silu(z).
__global__ __launch_bounds__(256)
void scan_pass3(const u16* __restrict__ dtb, const u16* __restrict__ xact,
                const u16* __restrict__ xz, const float* __restrict__ A_log,
                const float* __restrict__ Dp, const float* __restrict__ hbuf,
                u16* __restrict__ yg) {
  const int gid = blockIdx.x * 256 + threadIdx.x;
  const int c  = gid & (DINNER - 1);
  const int ch = (gid >> 11) & (NCH - 1);
  const int b  = gid >> 17;
  float a2[16];
#pragma unroll
  for (int s = 0; s < 16; ++s)
    a2[s] = -__expf(A_log[c * DSTATE + s]) * LOG2E;
  const float dp = Dp[c];
  float h[16];
  const float4* hi = (const float4*)&hbuf[(((size_t)(b * NCH + ch) * DINNER) + c) << 4];
#pragma unroll
  for (int q = 0; q < 4; ++q) {
    float4 v = hi[q];
    h[4 * q] = v.x; h[4 * q + 1] = v.y; h[4 * q + 2] = v.z; h[4 * q + 3] = v.w;
  }
  const size_t base = ((size_t)(b * LSEQ + ch * LC) << 11) + c;
  const size_t zbase = ((size_t)(b * LSEQ + ch * LC) << 12) + DINNER + c;
  for (int j = 0; j < LC; ++j) {
    const float dt = bf2f(dtb[base + ((size_t)j << 11)]);
    const float xv = bf2f(xact[base + ((size_t)j << 11)]);
    const float dx = dt * xv;
#pragma unroll
    for (int s = 0; s < 16; ++s)
      h[s] = fmaf(exp2f(dt * a2[s]), h[s], dx);
    float y = 0.f;
#pragma unroll
    for (int q = 0; q < 4; ++q)
      y += (h[4 * q] + h[4 * q + 1]) + (h[4 * q + 2] + h[4 * q + 3]);
    y = fmaf(dp, xv, y);
    const float zv = bf2f(xz[zbase + ((size_t)j << 12)]);
    yg[base + ((size_t)j << 11)] = f2bf(y * silu_f(zv));
  }
}

extern "C" void kernel_launch(void* const* d_in, const int* in_sizes, int n_in,
                              void* d_out, int out_size, void* d_ws, size_t ws_size,
                              hipStream_t stream) {
  const float* x      = (const float*)d_in[0];
  const float* W_in   = (const float*)d_in[1];
  const float* conv_w = (const float*)d_in[2];
  const float* conv_b = (const float*)d_in[3];
  const float* A_log  = (const float*)d_in[4];
  const float* Dp     = (const float*)d_in[5];
  const float* W_dt   = (const float*)d_in[6];
  const float* b_dt   = (const float*)d_in[7];
  const float* W_out  = (const float*)d_in[8];
  float* out = (float*)d_out;

  // workspace layout (~133 MB)
  float* ws    = (float*)d_ws;
  float* hbuf  = ws;                                     // [B,NCH,D,16] f32 16 MB
  float* sumdt = hbuf + (size_t)BSZ * NCH * DINNER * 16; // [B,NCH,D]   f32   1 MB
  u16* xz   = (u16*)(sumdt + (size_t)BSZ * NCH * DINNER);// [4096,4096] bf16 32 MB
  u16* dtb  = xz   + (size_t)MTOT * 2 * DINNER;          // [4096,2048] bf16 16 MB
  u16* xbf  = dtb  + (size_t)MTOT * DINNER;              // x bf16            8 MB
  u16* wibf = xbf  + (size_t)MTOT * DMODEL;              // W_in bf16         8 MB
  u16* wdbf = wibf + (size_t)2 * DINNER * DMODEL;        // W_dt bf16         8 MB
  u16* wobf = wdbf + (size_t)DINNER * DINNER;            // W_out bf16        4 MB
  u16* xact = wobf + (size_t)DMODEL * DINNER;            // x_act bf16       16 MB
  u16* yg   = xact + (size_t)MTOT * DINNER;              // y_gated bf16     16 MB

  const dim3 blk(256);

  // 0) all casts in one dispatch
  const int n0 = MTOT * DMODEL / 4, n1 = 2 * DINNER * DMODEL / 4;
  const int n2 = DINNER * DINNER / 4, n3 = DMODEL * DINNER / 4;
  cast4<<<(n0 + n1 + n2 + n3) / 256, blk, 0, stream>>>(
      (const float4*)x, (ushort4*)xbf, n0,
      (const float4*)W_in, (ushort4*)wibf, n1,
      (const float4*)W_dt, (ushort4*)wdbf, n2,
      (const float4*)W_out, (ushort4*)wobf, n3);

  // 1) xz = x @ W_in^T (bf16 out)
  hgemm_bt<0, 1><<<(MTOT / 128) * (2 * DINNER / 128), blk, 0, stream>>>(
      xbf, wibf, nullptr, xz, MTOT, 2 * DINNER, DMODEL);
  // 2) x_act = silu(conv(x_proj) + conv_b), bf16
  conv_silu<<<(MTOT * DINNER) / 256, blk, 0, stream>>>(xz, conv_w, conv_b, xact);
  // 3) dt = softplus(x_act @ W_dt^T + b_dt), bf16 out
  hgemm_bt<1, 1><<<(MTOT / 128) * (DINNER / 128), blk, 0, stream>>>(
      xact, wdbf, b_dt, dtb, MTOT, DINNER, DINNER);
  // 4) chunked selective scan + D skip + gate
  scan_pass1<<<BSZ * NCH * DINNER / 256, blk, 0, stream>>>(dtb, xact, A_log, hbuf, sumdt);
  scan_combine<<<BSZ * DINNER * 16 / 256, blk, 0, stream>>>(hbuf, sumdt, A_log);
  scan_pass3<<<BSZ * NCH * DINNER / 256, blk, 0, stream>>>(dtb, xact, xz, A_log, Dp, hbuf, yg);
  // 5) out = y_gated @ W_out^T (fp32 out)
  hgemm_bt<0, 0><<<(MTOT / 128) * (DMODEL / 128), blk, 0, stream>>>(
      yg, wobf, nullptr, out, MTOT, DMODEL, DINNER);
}

// Round 5
// 355.221 us; speedup vs baseline: 4.7957x; 1.1283x over previous
//
#include <hip/hip_runtime.h>

#define DMODEL 1024
#define DSTATE 16
#define DCONV  4
#define DINNER 2048
#define BSZ    2
#define LSEQ   2048
#define MTOT   (BSZ * LSEQ)   // 4096 rows for all GEMMs
#define NCH    64             // scan chunks per sequence
#define LC     (LSEQ / NCH)   // 32 timesteps per chunk
#define LOG2E  1.44269504088896f

typedef unsigned short u16;
typedef __attribute__((ext_vector_type(8))) short short8;  // 8 bf16 = 4 VGPRs (MFMA A/B frag)
typedef __attribute__((ext_vector_type(4))) float f32x4;   // MFMA C/D frag

// fast silu: v * rcp(1 + exp2(-v*log2e)) — v_rcp_f32 instead of the ~10-op
// precise-division expansion (output is bf16-rounded; rcp's ~1ulp is invisible)
__device__ __forceinline__ float silu_f(float v) {
  return v * __builtin_amdgcn_rcpf(1.f + __builtin_amdgcn_exp2f(-v * LOG2E));
}

__device__ __forceinline__ u16 f2bf(float f) {   // RNE f32 -> bf16
  unsigned int u = __float_as_uint(f);
  u += 0x7FFF + ((u >> 16) & 1);
  return (u16)(u >> 16);
}
__device__ __forceinline__ float bf2f(u16 b) { return __uint_as_float(((unsigned int)b) << 16); }

// async global->LDS, 16B per lane; LDS dest is wave-uniform base + lane*16 (m104)
__device__ __forceinline__ void gload_lds16(const u16* g, u16* l) {
  __builtin_amdgcn_global_load_lds((const __attribute__((address_space(1))) unsigned int*)g,
                                   (__attribute__((address_space(3))) unsigned int*)l, 16, 0, 0);
}

// All four f32->bf16 casts in one dispatch (x, W_in, W_dt, W_out)
__global__ __launch_bounds__(256)
void cast4(const float4* __restrict__ s0, ushort4* __restrict__ d0, int n0,
           const float4* __restrict__ s1, ushort4* __restrict__ d1, int n1,
           const float4* __restrict__ s2, ushort4* __restrict__ d2, int n2,
           const float4* __restrict__ s3, ushort4* __restrict__ d3, int n3) {
  int i = blockIdx.x * 256 + threadIdx.x;
  const float4* s; ushort4* d;
  if (i < n0)                { s = s0; d = d0; }
  else if ((i -= n0) < n1)   { s = s1; d = d1; }
  else if ((i -= n1) < n2)   { s = s2; d = d2; }
  else if ((i -= n2) < n3)   { s = s3; d = d3; }
  else return;
  float4 v = s[i];
  ushort4 o = { f2bf(v.x), f2bf(v.y), f2bf(v.z), f2bf(v.w) };
  d[i] = o;
}

// C[M,N] = A[M,K] @ B[N,K]^T, bf16 inputs.
// m97 structure: 128x128 tile, BK=32, 4 waves, 4x4 mfma_16x16x32 tiles per wave.
// 1-D grid with GROUP_M=4 panel swizzle for L2 locality.
// MODE 0: plain. MODE 1: softplus(C + bias[col]).  OBF: 1 -> bf16 C, 0 -> fp32 C.
template<int MODE, int OBF>
__global__ __launch_bounds__(256)
void hgemm_bt(const u16* __restrict__ A, const u16* __restrict__ B,
              const float* __restrict__ bias, void* __restrict__ Cv,
              int M, int N, int K) {
  __shared__ u16 As[128 * 32];   // 8 KB
  __shared__ u16 Bs[128 * 32];   // 8 KB
  const int tid  = threadIdx.x;
  const int lane = tid & 63;
  const int w    = tid >> 6;
  const int quad = lane >> 4;
  const int l16  = lane & 15;

  // GROUP_M=4 panel swizzle (triton-style): blocks in a panel share A rows
  const int nbn = N >> 7, nbm = M >> 7;
  const int pid = blockIdx.x;
  const int npg = 4 * nbn;
  const int fm  = (pid / npg) * 4;
  const int gsz = (nbm - fm < 4) ? (nbm - fm) : 4;
  const int bm  = (fm + (pid % gsz)) << 7;
  const int bn  = ((pid % npg) / gsz) << 7;

  const int wm = (w & 1) * 64;
  const int wn = (w >> 1) * 64;

  const int s0 = w * 2, s1 = s0 + 1;
  const int cg0 = (s0 << 6) + lane, cg1 = (s1 << 6) + lane;
  const int r0 = cg0 >> 2, r1 = cg1 >> 2;
  const int cd0 = (cg0 & 3) ^ ((r0 >> 1) & 3);
  const int cd1 = (cg1 & 3) ^ ((r1 >> 1) & 3);
  const u16* Ag0 = A + (size_t)(bm + r0) * K + (cd0 << 3);
  const u16* Ag1 = A + (size_t)(bm + r1) * K + (cd1 << 3);
  const u16* Bg0 = B + (size_t)(bn + r0) * K + (cd0 << 3);
  const u16* Bg1 = B + (size_t)(bn + r1) * K + (cd1 << 3);
  u16* Al0 = &As[s0 << 9];
  u16* Al1 = &As[s1 << 9];
  u16* Bl0 = &Bs[s0 << 9];
  u16* Bl1 = &Bs[s1 << 9];

  const short8* Afp[4];
  const short8* Bfp[4];
#pragma unroll
  for (int s = 0; s < 4; ++s) {
    const int ra = wm + 16 * s + l16;
    const int rb = wn + 16 * s + l16;
    Afp[s] = (const short8*)&As[ra * 32 + ((quad ^ ((ra >> 1) & 3)) << 3)];
    Bfp[s] = (const short8*)&Bs[rb * 32 + ((quad ^ ((rb >> 1) & 3)) << 3)];
  }

  f32x4 acc[4][4] = {};

  for (int k0 = 0; k0 < K; k0 += 32) {
    gload_lds16(Ag0, Al0); gload_lds16(Ag1, Al1);
    gload_lds16(Bg0, Bl0); gload_lds16(Bg1, Bl1);
    Ag0 += 32; Ag1 += 32; Bg0 += 32; Bg1 += 32;
    __syncthreads();
    short8 af[4], bf[4];
#pragma unroll
    for (int s = 0; s < 4; ++s) { af[s] = *Afp[s]; bf[s] = *Bfp[s]; }
#pragma unroll
    for (int ti = 0; ti < 4; ++ti)
#pragma unroll
      for (int tj = 0; tj < 4; ++tj)
        acc[ti][tj] = __builtin_amdgcn_mfma_f32_16x16x32_bf16(af[ti], bf[tj], acc[ti][tj], 0, 0, 0);
    __syncthreads();
  }

  // C/D layout: col = lane&15, row = quad*4 + reg (m89/m91)
#pragma unroll
  for (int ti = 0; ti < 4; ++ti) {
    const int row0 = bm + wm + 16 * ti + quad * 4;
#pragma unroll
    for (int tj = 0; tj < 4; ++tj) {
      const int col = bn + wn + 16 * tj + l16;
      const float bv = (MODE == 1) ? bias[col] : 0.f;
#pragma unroll
      for (int i = 0; i < 4; ++i) {
        float v = acc[ti][tj][i] + bv;
        if (MODE == 1) v = (v > 20.f) ? v : __logf(1.f + __expf(v));   // softplus
        if (OBF) ((u16*)Cv)[(size_t)(row0 + i) * N + col] = f2bf(v);
        else     ((float*)Cv)[(size_t)(row0 + i) * N + col] = v;
      }
    }
  }
}

// depthwise causal conv1d (taps=4, left pad 3) + bias + SiLU; bf16 in/out
__global__ __launch_bounds__(256)
void conv_silu(const u16* __restrict__ xz, const float* __restrict__ conv_w,
               const float* __restrict__ conv_b, u16* __restrict__ xact) {
  const int i = blockIdx.x * 256 + threadIdx.x;  // over MTOT*DINNER = 2^23
  const int c = i & (DINNER - 1);
  const int t = (i >> 11) & (LSEQ - 1);
  const int b = i >> 22;
  float s = conv_b[c];
  const float* w = conv_w + c * DCONV;
#pragma unroll
  for (int k = 0; k < DCONV; ++k) {
    const int tt = t + k - (DCONV - 1);
    if (tt >= 0)
      s = fmaf(bf2f(xz[((size_t)(b * LSEQ + tt) << 12) + c]), w[k], s);
  }
  xact[i] = f2bf(silu_f(s));
}

// ---- chunked parallel scan (exact decomposition of the linear recurrence) --

// Pass 1: per-chunk local scan from h=0 -> h_end[16]; also sum(dt) over chunk.
// launch_bounds(256,2): VGPR cap 256 so h[16]+a2[16] stay in registers (the
// default allocation spilled them -> 61us pass3 at VGPR_Count=32).
__global__ __launch_bounds__(256, 2)
void scan_pass1(const u16* __restrict__ dtb, const u16* __restrict__ xact,
                const float* __restrict__ A_log,
                float* __restrict__ hbuf, float* __restrict__ sumdt) {
  const int gid = blockIdx.x * 256 + threadIdx.x;  // 2^18 lanes
  const int c  = gid & (DINNER - 1);
  const int ch = (gid >> 11) & (NCH - 1);
  const int b  = gid >> 17;
  float a2[16];
#pragma unroll
  for (int s = 0; s < 16; ++s)
    a2[s] = -__expf(A_log[c * DSTATE + s]) * LOG2E;   // exp(dt*a) = exp2(dt*a2)
  const size_t base = ((size_t)(b * LSEQ + ch * LC) << 11) + c;
  float h[16] = {};
  float sd = 0.f;
  for (int j = 0; j < LC; j += 2) {
    // both steps' loads issued up front (2 in flight)
    const float dt0 = bf2f(dtb [base + ((size_t)j << 11)]);
    const float xv0 = bf2f(xact[base + ((size_t)j << 11)]);
    const float dt1 = bf2f(dtb [base + ((size_t)(j + 1) << 11)]);
    const float xv1 = bf2f(xact[base + ((size_t)(j + 1) << 11)]);
    const float dx0 = dt0 * xv0, dx1 = dt1 * xv1;
    sd += dt0 + dt1;
#pragma unroll
    for (int s = 0; s < 16; ++s)
      h[s] = fmaf(__builtin_amdgcn_exp2f(dt0 * a2[s]), h[s], dx0);
#pragma unroll
    for (int s = 0; s < 16; ++s)
      h[s] = fmaf(__builtin_amdgcn_exp2f(dt1 * a2[s]), h[s], dx1);
  }
  float4* ho = (float4*)&hbuf[(((size_t)(b * NCH + ch) * DINNER) + c) << 4];
#pragma unroll
  for (int q = 0; q < 4; ++q) {
    float4 v = { h[4 * q], h[4 * q + 1], h[4 * q + 2], h[4 * q + 3] };
    ho[q] = v;
  }
  sumdt[(size_t)(b * NCH + ch) * DINNER + c] = sd;
}

// Pass 2: serial combine over chunks; lane per (b,c,s). hbuf becomes h_start.
__global__ __launch_bounds__(256)
void scan_combine(float* __restrict__ hbuf, const float* __restrict__ sumdt,
                  const float* __restrict__ A_log) {
  const int gid = blockIdx.x * 256 + threadIdx.x;  // 2^16: b*32768 + c*16 + s
  const int s = gid & 15;
  const int c = (gid >> 4) & (DINNER - 1);
  const int b = gid >> 15;
  const float a2 = -__expf(A_log[c * DSTATE + s]) * LOG2E;
  float h = 0.f;
  for (int k = 0; k < NCH; ++k) {
    const size_t o = (((size_t)(b * NCH + k) * DINNER) + c) * 16 + s;
    const float he = hbuf[o];
    const float sd = sumdt[(size_t)(b * NCH + k) * DINNER + c];
    hbuf[o] = h;                          // h_start for chunk k
    h = fmaf(__builtin_amdgcn_exp2f(sd * a2), h, he);
  }
}

// Pass 3: re-scan each chunk from h_start; y = sum_s h + Dp*x; gate silu(z).
__global__ __launch_bounds__(256, 2)
void scan_pass3(const u16* __restrict__ dtb, const u16* __restrict__ xact,
                const u16* __restrict__ xz, const float* __restrict__ A_log,
                const float* __restrict__ Dp, const float* __restrict__ hbuf,
                u16* __restrict__ yg) {
  const int gid = blockIdx.x * 256 + threadIdx.x;
  const int c  = gid & (DINNER - 1);
  const int ch = (gid >> 11) & (NCH - 1);
  const int b  = gid >> 17;
  float a2[16];
#pragma unroll
  for (int s = 0; s < 16; ++s)
    a2[s] = -__expf(A_log[c * DSTATE + s]) * LOG2E;
  const float dp = Dp[c];
  float h[16];
  const float4* hi = (const float4*)&hbuf[(((size_t)(b * NCH + ch) * DINNER) + c) << 4];
#pragma unroll
  for (int q = 0; q < 4; ++q) {
    float4 v = hi[q];
    h[4 * q] = v.x; h[4 * q + 1] = v.y; h[4 * q + 2] = v.z; h[4 * q + 3] = v.w;
  }
  const size_t base  = ((size_t)(b * LSEQ + ch * LC) << 11) + c;
  const size_t zbase = ((size_t)(b * LSEQ + ch * LC) << 12) + DINNER + c;
  for (int j = 0; j < LC; j += 2) {
    const float dt0 = bf2f(dtb [base + ((size_t)j << 11)]);
    const float xv0 = bf2f(xact[base + ((size_t)j << 11)]);
    const float zv0 = bf2f(xz[zbase + ((size_t)j << 12)]);
    const float dt1 = bf2f(dtb [base + ((size_t)(j + 1) << 11)]);
    const float xv1 = bf2f(xact[base + ((size_t)(j + 1) << 11)]);
    const float zv1 = bf2f(xz[zbase + ((size_t)(j + 1) << 12)]);
    const float dx0 = dt0 * xv0, dx1 = dt1 * xv1;
    float y0 = 0.f, y1 = 0.f;
#pragma unroll
    for (int s = 0; s < 16; ++s) {
      h[s] = fmaf(__builtin_amdgcn_exp2f(dt0 * a2[s]), h[s], dx0);
      y0 += h[s];
    }
#pragma unroll
    for (int s = 0; s < 16; ++s) {
      h[s] = fmaf(__builtin_amdgcn_exp2f(dt1 * a2[s]), h[s], dx1);
      y1 += h[s];
    }
    y0 = fmaf(dp, xv0, y0);
    y1 = fmaf(dp, xv1, y1);
    yg[base + ((size_t)j << 11)]       = f2bf(y0 * silu_f(zv0));
    yg[base + ((size_t)(j + 1) << 11)] = f2bf(y1 * silu_f(zv1));
  }
}

extern "C" void kernel_launch(void* const* d_in, const int* in_sizes, int n_in,
                              void* d_out, int out_size, void* d_ws, size_t ws_size,
                              hipStream_t stream) {
  const float* x      = (const float*)d_in[0];
  const float* W_in   = (const float*)d_in[1];
  const float* conv_w = (const float*)d_in[2];
  const float* conv_b = (const float*)d_in[3];
  const float* A_log  = (const float*)d_in[4];
  const float* Dp     = (const float*)d_in[5];
  const float* W_dt   = (const float*)d_in[6];
  const float* b_dt   = (const float*)d_in[7];
  const float* W_out  = (const float*)d_in[8];
  float* out = (float*)d_out;

  // workspace layout (~133 MB)
  float* ws    = (float*)d_ws;
  float* hbuf  = ws;                                     // [B,NCH,D,16] f32 16 MB
  float* sumdt = hbuf + (size_t)BSZ * NCH * DINNER * 16; // [B,NCH,D]   f32   1 MB
  u16* xz   = (u16*)(sumdt + (size_t)BSZ * NCH * DINNER);// [4096,4096] bf16 32 MB
  u16* dtb  = xz   + (size_t)MTOT * 2 * DINNER;          // [4096,2048] bf16 16 MB
  u16* xbf  = dtb  + (size_t)MTOT * DINNER;              // x bf16            8 MB
  u16* wibf = xbf  + (size_t)MTOT * DMODEL;              // W_in bf16         8 MB
  u16* wdbf = wibf + (size_t)2 * DINNER * DMODEL;        // W_dt bf16         8 MB
  u16* wobf = wdbf + (size_t)DINNER * DINNER;            // W_out bf16        4 MB
  u16* xact = wobf + (size_t)DMODEL * DINNER;            // x_act bf16       16 MB
  u16* yg   = xact + (size_t)MTOT * DINNER;              // y_gated bf16     16 MB

  const dim3 blk(256);

  // 0) all casts in one dispatch
  const int n0 = MTOT * DMODEL / 4, n1 = 2 * DINNER * DMODEL / 4;
  const int n2 = DINNER * DINNER / 4, n3 = DMODEL * DINNER / 4;
  cast4<<<(n0 + n1 + n2 + n3) / 256, blk, 0, stream>>>(
      (const float4*)x, (ushort4*)xbf, n0,
      (const float4*)W_in, (ushort4*)wibf, n1,
      (const float4*)W_dt, (ushort4*)wdbf, n2,
      (const float4*)W_out, (ushort4*)wobf, n3);

  // 1) xz = x @ W_in^T (bf16 out)
  hgemm_bt<0, 1><<<(MTOT / 128) * (2 * DINNER / 128), blk, 0, stream>>>(
      xbf, wibf, nullptr, xz, MTOT, 2 * DINNER, DMODEL);
  // 2) x_act = silu(conv(x_proj) + conv_b), bf16
  conv_silu<<<(MTOT * DINNER) / 256, blk, 0, stream>>>(xz, conv_w, conv_b, xact);
  // 3) dt = softplus(x_act @ W_dt^T + b_dt), bf16 out
  hgemm_bt<1, 1><<<(MTOT / 128) * (DINNER / 128), blk, 0, stream>>>(
      xact, wdbf, b_dt, dtb, MTOT, DINNER, DINNER);
  // 4) chunked selective scan + D skip + gate
  scan_pass1<<<BSZ * NCH * DINNER / 256, blk, 0, stream>>>(dtb, xact, A_log, hbuf, sumdt);
  scan_combine<<<BSZ * DINNER * 16 / 256, blk, 0, stream>>>(hbuf, sumdt, A_log);
  scan_pass3<<<BSZ * NCH * DINNER / 256, blk, 0, stream>>>(dtb, xact, xz, A_log, Dp, hbuf, yg);
  // 5) out = y_gated @ W_out^T (fp32 out)
  hgemm_bt<0, 0><<<(MTOT / 128) * (DMODEL / 128), blk, 0, stream>>>(
      yg, wobf, nullptr, out, MTOT, DMODEL, DINNER);
}